// Round 13
// baseline (1070.605 us; speedup 1.0000x reference)
//
#include <hip/hip_runtime.h>
#include <hip/hip_bf16.h>
#include <cstdint>
#include <cstddef>

// Problem constants
#define NB 64      // batch
#define NT 256     // time steps
#define NL 64      // links
#define NH 128     // hidden
#define NN 16384   // nodes = NB*NT
#define NE 524288  // edges
#define NG 512     // 4*NH gates
#define NOUT 768   // 12*NL

// ---------------- small prep kernels ----------------

// Wt[n][k] = W[k][n], W is [K, Nout] row-major
__global__ __launch_bounds__(256) void k_transpose(const float* __restrict__ W,
                                                   float* __restrict__ Wt,
                                                   int K, int Nout) {
  int i = blockIdx.x * 256 + threadIdx.x;
  if (i < K * Nout) {
    int k = i / Nout, n = i % Nout;
    Wt[n * K + k] = W[i];
  }
}

// dvec[j] = sum_m dist[m] * W0[(64+m)*128 + j]   (128 blocks, one per j)
__global__ __launch_bounds__(256) void k_dvec(const float* __restrict__ dist,
                                              const float* __restrict__ W0,
                                              float* __restrict__ dvec) {
  __shared__ float red[256];
  int j = blockIdx.x;
  int t = threadIdx.x;
  float acc = 0.f;
  for (int m = t; m < 4096; m += 256)
    acc += dist[m] * W0[(size_t)(64 + m) * 128 + j];
  red[t] = acc;
  __syncthreads();
  for (int off = 128; off > 0; off >>= 1) {
    if (t < off) red[t] += red[t + off];
    __syncthreads();
  }
  if (t == 0) dvec[j] = red[0];
}

__global__ __launch_bounds__(256) void k_count(const int* __restrict__ dst,
                                               int* __restrict__ counts) {
  int i = blockIdx.x * 256 + threadIdx.x;
  atomicAdd(&counts[dst[i]], 1);
}

// exclusive scan of counts[16384] -> rowstart[16385]; also emits dinv (fused)
__global__ __launch_bounds__(1024) void k_scan(const int* __restrict__ counts,
                                               int* __restrict__ rowstart,
                                               float* __restrict__ dinv) {
  __shared__ int part[1024];
  int t = threadIdx.x;
  int base = t * 16;
  int local[16];
  int s = 0;
#pragma unroll
  for (int i = 0; i < 16; i++) {
    int cv = counts[base + i];
    local[i] = s; s += cv;
    dinv[base + i] = rsqrtf((float)cv + 1.0f);
  }
  part[t] = s;
  __syncthreads();
  for (int off = 1; off < 1024; off <<= 1) {
    int v = (t >= off) ? part[t - off] : 0;
    __syncthreads();
    part[t] += v;
    __syncthreads();
  }
  int prefix = (t == 0) ? 0 : part[t - 1];
#pragma unroll
  for (int i = 0; i < 16; i++) rowstart[base + i] = prefix + local[i];
  if (t == 1023) rowstart[16384] = part[1023];
}

__global__ __launch_bounds__(256) void k_fill(const int* __restrict__ src,
                                              const int* __restrict__ dst,
                                              const int* __restrict__ rowstart,
                                              int* __restrict__ fill,
                                              const float* __restrict__ dinv,
                                              int2* __restrict__ csr) {
  int e = blockIdx.x * 256 + threadIdx.x;
  int sN = src[e], dN = dst[e];
  int pos = rowstart[dN] + atomicAdd(&fill[dN], 1);
  csr[pos] = make_int2(sN, __float_as_int(dinv[sN] * dinv[dN]));
}

// ---------------- GEMM (no-LDS): C[M,Nn] = A[M,K] * B[Nn,K]^T (+bias0+bias1) ----
// R12 post-mortem: the LDS-tiled version is LDS-pipe-bound (per k4-epoch the
// shared LDS pipe owes 4 waves x 8 ds_read_b128 x 12cyc = 384 cyc vs 128 cyc of
// VALU; a 4x4 tile has reuse R=2, balance needs R=6). K is only 64/128 and B is
// a small L2-hot weight matrix shared by every block, so skip LDS entirely:
// A-fragment loads have 4 distinct addresses/wave (16-lane broadcast -> 64B
// coalesced), B-loads 16 distinct rows (256B/instr): ~1.25KB L2 traffic per
// wave-k4 (~40 B/cyc/CU demand) vs the measured ~125 B/cyc L2 rate -> VALU
// bound. No barriers, no LDS -> full occupancy, compiler pipelines the loads.
// PERMC: store col' = (col&127)*4 + (col>>7)  (gate-interleaved for LSTM pre)
template <int K, bool RELU, bool PERMC = false>
__global__ __launch_bounds__(256) void k_gemm_nolds(const float* __restrict__ A,
                                                    const float* __restrict__ Bm,
                                                    const float* __restrict__ bias0,
                                                    const float* __restrict__ bias1,
                                                    float* __restrict__ C, int Nn) {
  const int tid = threadIdx.x;
  const int row0 = blockIdx.x * 64 + ((tid >> 4) << 2);
  const int col0 = blockIdx.y * 64 + ((tid & 15) << 2);
  const float4* A0 = (const float4*)(A + (size_t)(row0 + 0) * K);
  const float4* A1 = (const float4*)(A + (size_t)(row0 + 1) * K);
  const float4* A2 = (const float4*)(A + (size_t)(row0 + 2) * K);
  const float4* A3 = (const float4*)(A + (size_t)(row0 + 3) * K);
  const float4* B0 = (const float4*)(Bm + (size_t)(col0 + 0) * K);
  const float4* B1 = (const float4*)(Bm + (size_t)(col0 + 1) * K);
  const float4* B2 = (const float4*)(Bm + (size_t)(col0 + 2) * K);
  const float4* B3 = (const float4*)(Bm + (size_t)(col0 + 3) * K);
  float acc[4][4] = {};
#pragma unroll 4
  for (int k4 = 0; k4 < K / 4; k4++) {
    float4 a0 = A0[k4], a1 = A1[k4], a2 = A2[k4], a3 = A3[k4];
    float4 b0 = B0[k4], b1 = B1[k4], b2 = B2[k4], b3 = B3[k4];
#define DOT4(i2, j2, av, bv)                                                   \
    acc[i2][j2] = fmaf(av.x, bv.x, acc[i2][j2]);                               \
    acc[i2][j2] = fmaf(av.y, bv.y, acc[i2][j2]);                               \
    acc[i2][j2] = fmaf(av.z, bv.z, acc[i2][j2]);                               \
    acc[i2][j2] = fmaf(av.w, bv.w, acc[i2][j2]);
    DOT4(0, 0, a0, b0) DOT4(0, 1, a0, b1) DOT4(0, 2, a0, b2) DOT4(0, 3, a0, b3)
    DOT4(1, 0, a1, b0) DOT4(1, 1, a1, b1) DOT4(1, 2, a1, b2) DOT4(1, 3, a1, b3)
    DOT4(2, 0, a2, b0) DOT4(2, 1, a2, b1) DOT4(2, 2, a2, b2) DOT4(2, 3, a2, b3)
    DOT4(3, 0, a3, b0) DOT4(3, 1, a3, b1) DOT4(3, 2, a3, b2) DOT4(3, 3, a3, b3)
#undef DOT4
  }
#pragma unroll
  for (int i2 = 0; i2 < 4; i2++) {
    int row = row0 + i2;
#pragma unroll
    for (int j2 = 0; j2 < 4; j2++) {
      int col = col0 + j2;
      float v = acc[i2][j2];
      if (bias0) v += bias0[col];
      if (bias1) v += bias1[col];
      if (RELU) v = fmaxf(v, 0.f);
      int colw = PERMC ? ((col & 127) * 4 + (col >> 7)) : col;
      C[(size_t)row * Nn + colw] = v;
    }
  }
}

// ---------------- GCN aggregation (float2 lanes, packed CSR, 4-edge unroll) ---------
__global__ __launch_bounds__(256) void k_agg(const float* __restrict__ h,
                                             const int* __restrict__ rowstart,
                                             const int2* __restrict__ csr,
                                             const float* __restrict__ dinv,
                                             const float* __restrict__ bias,
                                             float* __restrict__ out) {
  int node = blockIdx.x * 4 + (threadIdx.x >> 6);
  int lane = threadIdx.x & 63;
  int s = rowstart[node], e = rowstart[node + 1];
  const float2* h2 = (const float2*)h;
  float ax = 0.f, ay = 0.f;
  int p = s;
  for (; p + 3 < e; p += 4) {
    int2 pk0 = csr[p];
    int2 pk1 = csr[p + 1];
    int2 pk2 = csr[p + 2];
    int2 pk3 = csr[p + 3];
    float2 hv0 = h2[(size_t)pk0.x * 64 + lane];
    float2 hv1 = h2[(size_t)pk1.x * 64 + lane];
    float2 hv2 = h2[(size_t)pk2.x * 64 + lane];
    float2 hv3 = h2[(size_t)pk3.x * 64 + lane];
    float w0 = __int_as_float(pk0.y);
    float w1 = __int_as_float(pk1.y);
    float w2 = __int_as_float(pk2.y);
    float w3 = __int_as_float(pk3.y);
    ax = fmaf(hv0.x, w0, ax); ay = fmaf(hv0.y, w0, ay);
    ax = fmaf(hv1.x, w1, ax); ay = fmaf(hv1.y, w1, ay);
    ax = fmaf(hv2.x, w2, ax); ay = fmaf(hv2.y, w2, ay);
    ax = fmaf(hv3.x, w3, ax); ay = fmaf(hv3.y, w3, ay);
  }
  for (; p < e; p++) {
    int2 pk0 = csr[p];
    float2 hv0 = h2[(size_t)pk0.x * 64 + lane];
    float w0 = __int_as_float(pk0.y);
    ax = fmaf(hv0.x, w0, ax); ay = fmaf(hv0.y, w0, ay);
  }
  float di = dinv[node];
  float sw = di * di;
  float2 hs = h2[(size_t)node * 64 + lane];
  float2 bv = ((const float2*)bias)[lane];
  ax = fmaf(hs.x, sw, ax) + bv.x;
  ay = fmaf(hs.y, sw, ay) + bv.y;
  float2 o;
  o.x = fmaxf(ax, 0.f);
  o.y = fmaxf(ay, 0.f);
  ((float2*)out)[(size_t)node * 64 + lane] = o;
}

// ---------------- LSTM recurrence (R7 structure, best measured: 213 us/layer) -------
// Frozen verdict after 10 variants (R2-R12): f32 weights, named f4v registers with
// in-loop pins, waves_per_eu(2,2). The compiler services the pins via its own
// scratch/L2 reload schedule, which streams at the per-CU L2 floor (~830ns/step);
// every hand-written alternative (bf16 LDS, bf16 L2 pipelines, dual-pipe hybrid)
// measured slower (344 / 509 / 461 / 273 us vs 213).

template <int CTRL>
__device__ __forceinline__ float dppadd(float x) {
  int r = __builtin_amdgcn_update_dpp(0, __float_as_int(x), CTRL, 0xF, 0xF, true);
  return x + __int_as_float(r);
}
// quad_perm[1,0,3,2] = 0xB1 (xor1), quad_perm[2,3,0,1] = 0x4E (xor2)

__device__ __forceinline__ float sigf(float x) {
  return 1.f / (1.f + __expf(-x));
}
__device__ __forceinline__ float tanhf_fast(float x) {
  return 1.f - 2.f / (__expf(2.f * x) + 1.f);
}

typedef float f4v __attribute__((ext_vector_type(4)));

template <bool LAST_ONLY>
__global__ __launch_bounds__(512)
__attribute__((amdgpu_waves_per_eu(2, 2)))
void k_lstm7(const float* __restrict__ pre,
             const float* __restrict__ Whh,
             float* __restrict__ yout) {
  __shared__ float hbuf[2][128];
  const int tid = threadIdx.x;
  const int b = blockIdx.x;
  const int c4 = tid & 3;   // k-quarter
  const int u = tid >> 2;   // hidden unit 0..127

  // rotated float4 indices into h (R2-verified conflict-free pattern)
  int hidx[8];
#pragma unroll
  for (int j = 0; j < 8; j++) hidx[j] = c4 * 8 + (((u & 7) + 2 * c4 + j) & 7);

  // 32 named weight fragments: Wg_j = Whh[g*128+u][4*hidx[j] .. +3]
#define DECLW(g, j) \
  f4v W##g##_##j = *(const f4v*)(Whh + (size_t)((g)*128 + u) * 128 + hidx[j] * 4);
#define DECLW_ROW(g) \
  DECLW(g, 0) DECLW(g, 1) DECLW(g, 2) DECLW(g, 3) \
  DECLW(g, 4) DECLW(g, 5) DECLW(g, 6) DECLW(g, 7)
  DECLW_ROW(0) DECLW_ROW(1) DECLW_ROW(2) DECLW_ROW(3)
#undef DECLW_ROW
#undef DECLW

  if (tid < 128) hbuf[0][tid] = 0.f;
  float cs = 0.f;
  const float* preb = pre + (size_t)b * NT * NG + tid;  // tid == u*4 + c4 == P' column
  float pcur = preb[0];
  float* ybase = LAST_ONLY ? (yout + (size_t)b * NH + u)
                           : (yout + (size_t)b * NT * NH + u);
  __syncthreads();

#define PINW(g) \
  asm volatile("" : "+v"(W##g##_0), "+v"(W##g##_1), "+v"(W##g##_2), "+v"(W##g##_3)); \
  asm volatile("" : "+v"(W##g##_4), "+v"(W##g##_5), "+v"(W##g##_6), "+v"(W##g##_7));

#define FMA_J(j)                                                               \
  {                                                                            \
    f4v hv = hp[hidx[j]];                                                      \
    a0 = __builtin_elementwise_fma(W0_##j, hv, a0);                            \
    a1 = __builtin_elementwise_fma(W1_##j, hv, a1);                            \
    a2 = __builtin_elementwise_fma(W2_##j, hv, a2);                            \
    a3 = __builtin_elementwise_fma(W3_##j, hv, a3);                            \
  }

#define LSTM_STEP(CUR, NXT, T)                                                 \
  {                                                                            \
    int tn = (T) + 1; if (tn > NT - 1) tn = NT - 1;                            \
    float pnext = preb[(size_t)tn * NG];                                       \
    const f4v* hp = (const f4v*)&hbuf[CUR][0];                                 \
    f4v a0 = {0.f, 0.f, 0.f, 0.f}, a1 = a0, a2 = a0, a3 = a0;                  \
    FMA_J(0) FMA_J(1) FMA_J(2) FMA_J(3)                                        \
    FMA_J(4) FMA_J(5) FMA_J(6) FMA_J(7)                                        \
    float s0 = (a0.x + a0.y) + (a0.z + a0.w) + ((c4 == 0) ? pcur : 0.f);       \
    float s1 = (a1.x + a1.y) + (a1.z + a1.w) + ((c4 == 1) ? pcur : 0.f);       \
    float s2 = (a2.x + a2.y) + (a2.z + a2.w) + ((c4 == 2) ? pcur : 0.f);       \
    float s3 = (a3.x + a3.y) + (a3.z + a3.w) + ((c4 == 3) ? pcur : 0.f);       \
    s0 = dppadd<0xB1>(s0); s0 = dppadd<0x4E>(s0);                              \
    s1 = dppadd<0xB1>(s1); s1 = dppadd<0x4E>(s1);                              \
    s2 = dppadd<0xB1>(s2); s2 = dppadd<0x4E>(s2);                              \
    s3 = dppadd<0xB1>(s3); s3 = dppadd<0x4E>(s3);                              \
    float si = sigf(s0), sf = sigf(s1), tg = tanhf_fast(s2), so = sigf(s3);    \
    cs = sf * cs + si * tg;                                                    \
    float hnew = so * tanhf_fast(cs);                                          \
    if (c4 == 0) hbuf[NXT][u] = hnew;                                          \
    if (!LAST_ONLY) {                                                          \
      if (c4 == 1) ybase[(size_t)(T) * NH] = hnew;                             \
    } else if ((T) == NT - 1) {                                                \
      if (c4 == 1) *ybase = hnew;                                              \
    }                                                                          \
    pcur = pnext;                                                              \
    __syncthreads();                                                           \
  }

  for (int t = 0; t < NT; t += 2) {
    PINW(0) PINW(1) PINW(2) PINW(3)
    LSTM_STEP(0, 1, t);
    LSTM_STEP(1, 0, t + 1);
  }
#undef LSTM_STEP
#undef FMA_J
#undef PINW
}

// ---------------- host ----------------

extern "C" void kernel_launch(void* const* d_in, const int* in_sizes, int n_in,
                              void* d_out, int out_size, void* d_ws, size_t ws_size,
                              hipStream_t stream) {
  const float* x    = (const float*)d_in[0];   // [64,256,64] -> [16384,64]
  const float* dist = (const float*)d_in[1];   // [64,64]
  const int*   ei   = (const int*)d_in[2];     // [2, 524288]
  const float* W0   = (const float*)d_in[3];   // [4160,128]
  const float* b0   = (const float*)d_in[4];
  const float* W1   = (const float*)d_in[5];   // [128,128]
  const float* b1   = (const float*)d_in[6];
  const float* W2   = (const float*)d_in[7];
  const float* b2   = (const float*)d_in[8];
  const float* Wih0 = (const float*)d_in[9];   // [512,128]
  const float* Whh0 = (const float*)d_in[10];  // [512,128]
  const float* bih0 = (const float*)d_in[11];
  const float* bhh0 = (const float*)d_in[12];
  const float* Wih1 = (const float*)d_in[13];
  const float* Whh1 = (const float*)d_in[14];
  const float* bih1 = (const float*)d_in[15];
  const float* bhh1 = (const float*)d_in[16];
  const float* fcW  = (const float*)d_in[17];  // [768,128]
  const float* fcb  = (const float*)d_in[18];
  float* out = (float*)d_out;

  char* ws = (char*)d_ws;
  size_t off = 0;
  auto alloc = [&](size_t bytes) -> void* {
    void* p = ws + off;
    off += (bytes + 255) & ~(size_t)255;
    return p;
  };
  float* bufA     = (float*)alloc((size_t)NN * 128 * 4);
  float* bufB     = (float*)alloc((size_t)NN * 128 * 4);
  float* pre      = (float*)alloc((size_t)NN * 512 * 4);
  int2*  csr      = (int2*)alloc((size_t)NE * 8);
  int*   counts   = (int*)alloc((size_t)NN * 4);
  int*   fillc    = (int*)alloc((size_t)NN * 4);
  int*   rowstart = (int*)alloc((size_t)(NN + 1) * 4);
  float* dinv     = (float*)alloc((size_t)NN * 4);
  float* dvec     = (float*)alloc(128 * 4);
  float* hlast    = (float*)alloc(64 * 128 * 4);
  float* wt0      = (float*)alloc(128 * 64 * 4);
  float* wt1      = (float*)alloc(128 * 128 * 4);
  float* wt2      = (float*)alloc(128 * 128 * 4);
  (void)ws_size; (void)in_sizes; (void)n_in; (void)out_size;

  const int* srcIdx = ei;
  const int* dstIdx = ei + NE;

  hipMemsetAsync(counts, 0, (size_t)NN * 4, stream);
  hipMemsetAsync(fillc, 0, (size_t)NN * 4, stream);

  // weight transposes + distance vector
  k_transpose<<<(64 * 128 + 255) / 256, 256, 0, stream>>>(W0, wt0, 64, 128);
  k_transpose<<<(128 * 128 + 255) / 256, 256, 0, stream>>>(W1, wt1, 128, 128);
  k_transpose<<<(128 * 128 + 255) / 256, 256, 0, stream>>>(W2, wt2, 128, 128);
  k_dvec<<<128, 256, 0, stream>>>(dist, W0, dvec);

  // CSR build (reused by all 3 GCN layers); dinv fused into scan
  k_count<<<NE / 256, 256, 0, stream>>>(dstIdx, counts);
  k_scan<<<1, 1024, 0, stream>>>(counts, rowstart, dinv);
  k_fill<<<NE / 256, 256, 0, stream>>>(srcIdx, dstIdx, rowstart, fillc, dinv, csr);

  // GCN layer 0: h0 = x @ W0a^T + dvec  (bias/relu happen after aggregation)
  dim3 gH(NN / 64, 128 / 64);
  k_gemm_nolds<64, false><<<gH, 256, 0, stream>>>(x, wt0, dvec, nullptr, bufB, 128);
  k_agg<<<NN / 4, 256, 0, stream>>>(bufB, rowstart, csr, dinv, b0, bufA);
  // GCN layer 1
  k_gemm_nolds<128, false><<<gH, 256, 0, stream>>>(bufA, wt1, nullptr, nullptr, bufB, 128);
  k_agg<<<NN / 4, 256, 0, stream>>>(bufB, rowstart, csr, dinv, b1, bufA);
  // GCN layer 2
  k_gemm_nolds<128, false><<<gH, 256, 0, stream>>>(bufA, wt2, nullptr, nullptr, bufB, 128);
  k_agg<<<NN / 4, 256, 0, stream>>>(bufB, rowstart, csr, dinv, b2, bufA);

  // LSTM layer 0: pre (permuted) = feat @ Wih0^T + bih0 + bhh0 ; recurrence -> y1 (bufB)
  dim3 gP(NN / 64, 512 / 64);
  k_gemm_nolds<128, false, true><<<gP, 256, 0, stream>>>(bufA, Wih0, bih0, bhh0, pre, 512);
  k_lstm7<false><<<64, 512, 0, stream>>>(pre, Whh0, bufB);
  // LSTM layer 1
  k_gemm_nolds<128, false, true><<<gP, 256, 0, stream>>>(bufB, Wih1, bih1, bhh1, pre, 512);
  k_lstm7<true><<<64, 512, 0, stream>>>(pre, Whh1, hlast);

  // FC: out[64,768] = hlast @ fcW^T + fcb
  dim3 gF(1, NOUT / 64);
  k_gemm_nolds<128, false><<<gF, 256, 0, stream>>>(hlast, fcW, fcb, nullptr, out, NOUT);
}

// Round 14
// 756.442 us; speedup vs baseline: 1.4153x; 1.4153x over previous
//
#include <hip/hip_runtime.h>
#include <hip/hip_bf16.h>
#include <cstdint>
#include <cstddef>

// Problem constants
#define NB 64      // batch
#define NT 256     // time steps
#define NL 64      // links
#define NH 128     // hidden
#define NN 16384   // nodes = NB*NT
#define NE 524288  // edges
#define NG 512     // 4*NH gates
#define NOUT 768   // 12*NL

__device__ __forceinline__ unsigned rne_bf16(float f) {
  unsigned u = __float_as_uint(f);
  return (u + 0x7FFFu + ((u >> 16) & 1u)) >> 16;
}

// ---------------- small prep kernels ----------------

// Wt[n][k] = W[k][n], W is [K, Nout] row-major
__global__ __launch_bounds__(256) void k_transpose(const float* __restrict__ W,
                                                   float* __restrict__ Wt,
                                                   int K, int Nout) {
  int i = blockIdx.x * 256 + threadIdx.x;
  if (i < K * Nout) {
    int k = i / Nout, n = i % Nout;
    Wt[n * K + k] = W[i];
  }
}

// dvec[j] = sum_m dist[m] * W0[(64+m)*128 + j]   (128 blocks, one per j)
__global__ __launch_bounds__(256) void k_dvec(const float* __restrict__ dist,
                                              const float* __restrict__ W0,
                                              float* __restrict__ dvec) {
  __shared__ float red[256];
  int j = blockIdx.x;
  int t = threadIdx.x;
  float acc = 0.f;
  for (int m = t; m < 4096; m += 256)
    acc += dist[m] * W0[(size_t)(64 + m) * 128 + j];
  red[t] = acc;
  __syncthreads();
  for (int off = 128; off > 0; off >>= 1) {
    if (t < off) red[t] += red[t + off];
    __syncthreads();
  }
  if (t == 0) dvec[j] = red[0];
}

__global__ __launch_bounds__(256) void k_count(const int* __restrict__ dst,
                                               int* __restrict__ counts) {
  int i = blockIdx.x * 256 + threadIdx.x;
  atomicAdd(&counts[dst[i]], 1);
}

// exclusive scan of counts[16384] -> rowstart[16385]; also emits dinv (fused)
__global__ __launch_bounds__(1024) void k_scan(const int* __restrict__ counts,
                                               int* __restrict__ rowstart,
                                               float* __restrict__ dinv) {
  __shared__ int part[1024];
  int t = threadIdx.x;
  int base = t * 16;
  int local[16];
  int s = 0;
#pragma unroll
  for (int i = 0; i < 16; i++) {
    int cv = counts[base + i];
    local[i] = s; s += cv;
    dinv[base + i] = rsqrtf((float)cv + 1.0f);
  }
  part[t] = s;
  __syncthreads();
  for (int off = 1; off < 1024; off <<= 1) {
    int v = (t >= off) ? part[t - off] : 0;
    __syncthreads();
    part[t] += v;
    __syncthreads();
  }
  int prefix = (t == 0) ? 0 : part[t - 1];
#pragma unroll
  for (int i = 0; i < 16; i++) rowstart[base + i] = prefix + local[i];
  if (t == 1023) rowstart[16384] = part[1023];
}

__global__ __launch_bounds__(256) void k_fill(const int* __restrict__ src,
                                              const int* __restrict__ dst,
                                              const int* __restrict__ rowstart,
                                              int* __restrict__ fill,
                                              const float* __restrict__ dinv,
                                              int2* __restrict__ csr) {
  int e = blockIdx.x * 256 + threadIdx.x;
  int sN = src[e], dN = dst[e];
  int pos = rowstart[dN] + atomicAdd(&fill[dN], 1);
  csr[pos] = make_int2(sN, __float_as_int(dinv[sN] * dinv[dN]));
}

// ---------------- GEMM: C[M,Nn] = A[M,K] * B[Nn,K]^T (+bias0+bias1) ----------------
// XOR-swizzled float4 LDS groups (R11-verified, best measured).
// OBF16: store C as packed bf16 (RNE) -- used for GCN h, which only k_agg reads.
// PERMC: store col' = (col&127)*4 + (col>>7)  (gate-interleaved for LSTM pre)
template <int K, bool RELU, bool PERMC = false, bool OBF16 = false>
__global__ __launch_bounds__(256) void k_gemm_abt(const float* __restrict__ A,
                                                  const float* __restrict__ Bm,
                                                  const float* __restrict__ bias0,
                                                  const float* __restrict__ bias1,
                                                  void* __restrict__ Cv, int Nn) {
  __shared__ float As[64][K];
  __shared__ float Bs[64][K];
  const int tid = threadIdx.x;
  const int bm = blockIdx.x, bn = blockIdx.y;
  const int VPR = K / 4;  // float4 groups per row
  for (int i = tid; i < 64 * VPR; i += 256) {
    int r = i / VPR, c = i % VPR;
    int xr = (r >> 2) & 7;
    float4 q = *(const float4*)(A + (size_t)(bm * 64 + r) * K + c * 4);
    *(float4*)&As[r][(c ^ xr) * 4] = q;
  }
  for (int i = tid; i < 64 * VPR; i += 256) {
    int r = i / VPR, c = i % VPR;
    int xr = (r >> 2) & 7;
    float4 q = *(const float4*)(Bm + (size_t)(bn * 64 + r) * K + c * 4);
    *(float4*)&Bs[r][(c ^ xr) * 4] = q;
  }
  __syncthreads();
  const int tr = (tid >> 4) << 2;   // output rows tr..tr+3
  const int tc = (tid & 15) << 2;   // output cols tc..tc+3
  const int axor = (tr >> 2) & 7;
  const int bxor = (tc >> 2) & 7;
  float acc[4][4] = {};
#pragma unroll 2
  for (int k4 = 0; k4 < VPR; k4++) {
    int ka = (k4 ^ axor) * 4;
    int kb = (k4 ^ bxor) * 4;
    float4 a0 = *(const float4*)&As[tr + 0][ka];
    float4 a1 = *(const float4*)&As[tr + 1][ka];
    float4 a2 = *(const float4*)&As[tr + 2][ka];
    float4 a3 = *(const float4*)&As[tr + 3][ka];
    float4 b0 = *(const float4*)&Bs[tc + 0][kb];
    float4 b1 = *(const float4*)&Bs[tc + 1][kb];
    float4 b2 = *(const float4*)&Bs[tc + 2][kb];
    float4 b3 = *(const float4*)&Bs[tc + 3][kb];
#define DOT4(i2, j2, av, bv)                                                   \
    acc[i2][j2] = fmaf(av.x, bv.x, acc[i2][j2]);                               \
    acc[i2][j2] = fmaf(av.y, bv.y, acc[i2][j2]);                               \
    acc[i2][j2] = fmaf(av.z, bv.z, acc[i2][j2]);                               \
    acc[i2][j2] = fmaf(av.w, bv.w, acc[i2][j2]);
    DOT4(0, 0, a0, b0) DOT4(0, 1, a0, b1) DOT4(0, 2, a0, b2) DOT4(0, 3, a0, b3)
    DOT4(1, 0, a1, b0) DOT4(1, 1, a1, b1) DOT4(1, 2, a1, b2) DOT4(1, 3, a1, b3)
    DOT4(2, 0, a2, b0) DOT4(2, 1, a2, b1) DOT4(2, 2, a2, b2) DOT4(2, 3, a2, b3)
    DOT4(3, 0, a3, b0) DOT4(3, 1, a3, b1) DOT4(3, 2, a3, b2) DOT4(3, 3, a3, b3)
#undef DOT4
  }
  const int col0 = bn * 64 + tc;
#pragma unroll
  for (int i2 = 0; i2 < 4; i2++) {
    int row = bm * 64 + tr + i2;
    float v[4];
#pragma unroll
    for (int j2 = 0; j2 < 4; j2++) {
      int col = col0 + j2;
      float t = acc[i2][j2];
      if (bias0) t += bias0[col];
      if (bias1) t += bias1[col];
      if (RELU) t = fmaxf(t, 0.f);
      v[j2] = t;
    }
    if (OBF16) {
      unsigned short* C = (unsigned short*)Cv;
      uint2 pk;
      pk.x = rne_bf16(v[0]) | (rne_bf16(v[1]) << 16);
      pk.y = rne_bf16(v[2]) | (rne_bf16(v[3]) << 16);
      *(uint2*)(C + (size_t)row * Nn + col0) = pk;
    } else {
      float* C = (float*)Cv;
#pragma unroll
      for (int j2 = 0; j2 < 4; j2++) {
        int col = col0 + j2;
        int colw = PERMC ? ((col & 127) * 4 + (col >> 7)) : col;
        C[(size_t)row * Nn + colw] = v[j2];
      }
    }
  }
}

// ---------------- GCN aggregation: bf16 h gather, f32 accumulate/output -----------
// h is [NN][128] bf16 (packed pairs as uint). Per edge the wave reads 256B (was
// 512B f32) -- the gather is the tail's dominant LLC traffic (268->134 MB/layer).
typedef float f2v __attribute__((ext_vector_type(2)));
__device__ __forceinline__ f2v unpk2(unsigned d) {
  f2v r;
  r.x = __uint_as_float(d << 16);
  r.y = __uint_as_float(d & 0xFFFF0000u);
  return r;
}

__global__ __launch_bounds__(256) void k_agg(const unsigned* __restrict__ h,
                                             const int* __restrict__ rowstart,
                                             const int2* __restrict__ csr,
                                             const float* __restrict__ dinv,
                                             const float* __restrict__ bias,
                                             float* __restrict__ out) {
  int node = blockIdx.x * 4 + (threadIdx.x >> 6);
  int lane = threadIdx.x & 63;
  int s = rowstart[node], e = rowstart[node + 1];
  float ax = 0.f, ay = 0.f;
  int p = s;
  for (; p + 3 < e; p += 4) {
    int2 pk0 = csr[p];
    int2 pk1 = csr[p + 1];
    int2 pk2 = csr[p + 2];
    int2 pk3 = csr[p + 3];
    f2v hv0 = unpk2(h[(size_t)pk0.x * 64 + lane]);
    f2v hv1 = unpk2(h[(size_t)pk1.x * 64 + lane]);
    f2v hv2 = unpk2(h[(size_t)pk2.x * 64 + lane]);
    f2v hv3 = unpk2(h[(size_t)pk3.x * 64 + lane]);
    float w0 = __int_as_float(pk0.y);
    float w1 = __int_as_float(pk1.y);
    float w2 = __int_as_float(pk2.y);
    float w3 = __int_as_float(pk3.y);
    ax = fmaf(hv0.x, w0, ax); ay = fmaf(hv0.y, w0, ay);
    ax = fmaf(hv1.x, w1, ax); ay = fmaf(hv1.y, w1, ay);
    ax = fmaf(hv2.x, w2, ax); ay = fmaf(hv2.y, w2, ay);
    ax = fmaf(hv3.x, w3, ax); ay = fmaf(hv3.y, w3, ay);
  }
  for (; p < e; p++) {
    int2 pk0 = csr[p];
    f2v hv0 = unpk2(h[(size_t)pk0.x * 64 + lane]);
    float w0 = __int_as_float(pk0.y);
    ax = fmaf(hv0.x, w0, ax); ay = fmaf(hv0.y, w0, ay);
  }
  float di = dinv[node];
  float sw = di * di;
  f2v hs = unpk2(h[(size_t)node * 64 + lane]);
  float2 bv = ((const float2*)bias)[lane];
  ax = fmaf(hs.x, sw, ax) + bv.x;
  ay = fmaf(hs.y, sw, ay) + bv.y;
  float2 o;
  o.x = fmaxf(ax, 0.f);
  o.y = fmaxf(ay, 0.f);
  ((float2*)out)[(size_t)node * 64 + lane] = o;
}

// ---------------- LSTM recurrence (R7 structure, best measured: 213 us/layer) -------
// Frozen after 10 variants (R2-R12). f32 weights, named f4v regs, in-loop pins,
// waves_per_eu(2,2); compiler's scratch/L2 restream = the measured floor.

template <int CTRL>
__device__ __forceinline__ float dppadd(float x) {
  int r = __builtin_amdgcn_update_dpp(0, __float_as_int(x), CTRL, 0xF, 0xF, true);
  return x + __int_as_float(r);
}
// quad_perm[1,0,3,2] = 0xB1 (xor1), quad_perm[2,3,0,1] = 0x4E (xor2)

__device__ __forceinline__ float sigf(float x) {
  return 1.f / (1.f + __expf(-x));
}
__device__ __forceinline__ float tanhf_fast(float x) {
  return 1.f - 2.f / (__expf(2.f * x) + 1.f);
}

typedef float f4v __attribute__((ext_vector_type(4)));

template <bool LAST_ONLY>
__global__ __launch_bounds__(512)
__attribute__((amdgpu_waves_per_eu(2, 2)))
void k_lstm7(const float* __restrict__ pre,
             const float* __restrict__ Whh,
             float* __restrict__ yout) {
  __shared__ float hbuf[2][128];
  const int tid = threadIdx.x;
  const int b = blockIdx.x;
  const int c4 = tid & 3;   // k-quarter
  const int u = tid >> 2;   // hidden unit 0..127

  // rotated float4 indices into h (R2-verified conflict-free pattern)
  int hidx[8];
#pragma unroll
  for (int j = 0; j < 8; j++) hidx[j] = c4 * 8 + (((u & 7) + 2 * c4 + j) & 7);

  // 32 named weight fragments: Wg_j = Whh[g*128+u][4*hidx[j] .. +3]
#define DECLW(g, j) \
  f4v W##g##_##j = *(const f4v*)(Whh + (size_t)((g)*128 + u) * 128 + hidx[j] * 4);
#define DECLW_ROW(g) \
  DECLW(g, 0) DECLW(g, 1) DECLW(g, 2) DECLW(g, 3) \
  DECLW(g, 4) DECLW(g, 5) DECLW(g, 6) DECLW(g, 7)
  DECLW_ROW(0) DECLW_ROW(1) DECLW_ROW(2) DECLW_ROW(3)
#undef DECLW_ROW
#undef DECLW

  if (tid < 128) hbuf[0][tid] = 0.f;
  float cs = 0.f;
  const float* preb = pre + (size_t)b * NT * NG + tid;  // tid == u*4 + c4 == P' column
  float pcur = preb[0];
  float* ybase = LAST_ONLY ? (yout + (size_t)b * NH + u)
                           : (yout + (size_t)b * NT * NH + u);
  __syncthreads();

#define PINW(g) \
  asm volatile("" : "+v"(W##g##_0), "+v"(W##g##_1), "+v"(W##g##_2), "+v"(W##g##_3)); \
  asm volatile("" : "+v"(W##g##_4), "+v"(W##g##_5), "+v"(W##g##_6), "+v"(W##g##_7));

#define FMA_J(j)                                                               \
  {                                                                            \
    f4v hv = hp[hidx[j]];                                                      \
    a0 = __builtin_elementwise_fma(W0_##j, hv, a0);                            \
    a1 = __builtin_elementwise_fma(W1_##j, hv, a1);                            \
    a2 = __builtin_elementwise_fma(W2_##j, hv, a2);                            \
    a3 = __builtin_elementwise_fma(W3_##j, hv, a3);                            \
  }

#define LSTM_STEP(CUR, NXT, T)                                                 \
  {                                                                            \
    int tn = (T) + 1; if (tn > NT - 1) tn = NT - 1;                            \
    float pnext = preb[(size_t)tn * NG];                                       \
    const f4v* hp = (const f4v*)&hbuf[CUR][0];                                 \
    f4v a0 = {0.f, 0.f, 0.f, 0.f}, a1 = a0, a2 = a0, a3 = a0;                  \
    FMA_J(0) FMA_J(1) FMA_J(2) FMA_J(3)                                        \
    FMA_J(4) FMA_J(5) FMA_J(6) FMA_J(7)                                        \
    float s0 = (a0.x + a0.y) + (a0.z + a0.w) + ((c4 == 0) ? pcur : 0.f);       \
    float s1 = (a1.x + a1.y) + (a1.z + a1.w) + ((c4 == 1) ? pcur : 0.f);       \
    float s2 = (a2.x + a2.y) + (a2.z + a2.w) + ((c4 == 2) ? pcur : 0.f);       \
    float s3 = (a3.x + a3.y) + (a3.z + a3.w) + ((c4 == 3) ? pcur : 0.f);       \
    s0 = dppadd<0xB1>(s0); s0 = dppadd<0x4E>(s0);                              \
    s1 = dppadd<0xB1>(s1); s1 = dppadd<0x4E>(s1);                              \
    s2 = dppadd<0xB1>(s2); s2 = dppadd<0x4E>(s2);                              \
    s3 = dppadd<0xB1>(s3); s3 = dppadd<0x4E>(s3);                              \
    float si = sigf(s0), sf = sigf(s1), tg = tanhf_fast(s2), so = sigf(s3);    \
    cs = sf * cs + si * tg;                                                    \
    float hnew = so * tanhf_fast(cs);                                          \
    if (c4 == 0) hbuf[NXT][u] = hnew;                                          \
    if (!LAST_ONLY) {                                                          \
      if (c4 == 1) ybase[(size_t)(T) * NH] = hnew;                             \
    } else if ((T) == NT - 1) {                                                \
      if (c4 == 1) *ybase = hnew;                                              \
    }                                                                          \
    pcur = pnext;                                                              \
    __syncthreads();                                                           \
  }

  for (int t = 0; t < NT; t += 2) {
    PINW(0) PINW(1) PINW(2) PINW(3)
    LSTM_STEP(0, 1, t);
    LSTM_STEP(1, 0, t + 1);
  }
#undef LSTM_STEP
#undef FMA_J
#undef PINW
}

// ---------------- host ----------------

extern "C" void kernel_launch(void* const* d_in, const int* in_sizes, int n_in,
                              void* d_out, int out_size, void* d_ws, size_t ws_size,
                              hipStream_t stream) {
  const float* x    = (const float*)d_in[0];   // [64,256,64] -> [16384,64]
  const float* dist = (const float*)d_in[1];   // [64,64]
  const int*   ei   = (const int*)d_in[2];     // [2, 524288]
  const float* W0   = (const float*)d_in[3];   // [4160,128]
  const float* b0   = (const float*)d_in[4];
  const float* W1   = (const float*)d_in[5];   // [128,128]
  const float* b1   = (const float*)d_in[6];
  const float* W2   = (const float*)d_in[7];
  const float* b2   = (const float*)d_in[8];
  const float* Wih0 = (const float*)d_in[9];   // [512,128]
  const float* Whh0 = (const float*)d_in[10];  // [512,128]
  const float* bih0 = (const float*)d_in[11];
  const float* bhh0 = (const float*)d_in[12];
  const float* Wih1 = (const float*)d_in[13];
  const float* Whh1 = (const float*)d_in[14];
  const float* bih1 = (const float*)d_in[15];
  const float* bhh1 = (const float*)d_in[16];
  const float* fcW  = (const float*)d_in[17];  // [768,128]
  const float* fcb  = (const float*)d_in[18];
  float* out = (float*)d_out;

  char* ws = (char*)d_ws;
  size_t off = 0;
  auto alloc = [&](size_t bytes) -> void* {
    void* p = ws + off;
    off += (bytes + 255) & ~(size_t)255;
    return p;
  };
  float*    bufA     = (float*)alloc((size_t)NN * 128 * 4);
  float*    bufB     = (float*)alloc((size_t)NN * 128 * 4);
  unsigned short* h16 = (unsigned short*)alloc((size_t)NN * 128 * 2);
  float*    pre      = (float*)alloc((size_t)NN * 512 * 4);
  int2*     csr      = (int2*)alloc((size_t)NE * 8);
  int*      counts   = (int*)alloc((size_t)NN * 4);
  int*      fillc    = (int*)alloc((size_t)NN * 4);
  int*      rowstart = (int*)alloc((size_t)(NN + 1) * 4);
  float*    dinv     = (float*)alloc((size_t)NN * 4);
  float*    dvec     = (float*)alloc(128 * 4);
  float*    hlast    = (float*)alloc(64 * 128 * 4);
  float*    wt0      = (float*)alloc(128 * 64 * 4);
  float*    wt1      = (float*)alloc(128 * 128 * 4);
  float*    wt2      = (float*)alloc(128 * 128 * 4);
  (void)ws_size; (void)in_sizes; (void)n_in; (void)out_size;

  const int* srcIdx = ei;
  const int* dstIdx = ei + NE;

  hipMemsetAsync(counts, 0, (size_t)NN * 4, stream);
  hipMemsetAsync(fillc, 0, (size_t)NN * 4, stream);

  // weight transposes + distance vector
  k_transpose<<<(64 * 128 + 255) / 256, 256, 0, stream>>>(W0, wt0, 64, 128);
  k_transpose<<<(128 * 128 + 255) / 256, 256, 0, stream>>>(W1, wt1, 128, 128);
  k_transpose<<<(128 * 128 + 255) / 256, 256, 0, stream>>>(W2, wt2, 128, 128);
  k_dvec<<<128, 256, 0, stream>>>(dist, W0, dvec);

  // CSR build (reused by all 3 GCN layers); dinv fused into scan
  k_count<<<NE / 256, 256, 0, stream>>>(dstIdx, counts);
  k_scan<<<1, 1024, 0, stream>>>(counts, rowstart, dinv);
  k_fill<<<NE / 256, 256, 0, stream>>>(srcIdx, dstIdx, rowstart, fillc, dinv, csr);

  // GCN layer 0: h0 = x @ W0a^T + dvec (bf16 out) ; agg -> bufA (f32)
  dim3 gH(NN / 64, 128 / 64);
  k_gemm_abt<64, false, false, true><<<gH, 256, 0, stream>>>(x, wt0, dvec, nullptr, h16, 128);
  k_agg<<<NN / 4, 256, 0, stream>>>((const unsigned*)h16, rowstart, csr, dinv, b0, bufA);
  // GCN layer 1
  k_gemm_abt<128, false, false, true><<<gH, 256, 0, stream>>>(bufA, wt1, nullptr, nullptr, h16, 128);
  k_agg<<<NN / 4, 256, 0, stream>>>((const unsigned*)h16, rowstart, csr, dinv, b1, bufA);
  // GCN layer 2
  k_gemm_abt<128, false, false, true><<<gH, 256, 0, stream>>>(bufA, wt2, nullptr, nullptr, h16, 128);
  k_agg<<<NN / 4, 256, 0, stream>>>((const unsigned*)h16, rowstart, csr, dinv, b2, bufA);

  // LSTM layer 0: pre (permuted) = feat @ Wih0^T + bih0 + bhh0 ; recurrence -> y1 (bufB)
  dim3 gP(NN / 64, 512 / 64);
  k_gemm_abt<128, false, true><<<gP, 256, 0, stream>>>(bufA, Wih0, bih0, bhh0, pre, 512);
  k_lstm7<false><<<64, 512, 0, stream>>>(pre, Whh0, bufB);
  // LSTM layer 1
  k_gemm_abt<128, false, true><<<gP, 256, 0, stream>>>(bufB, Wih1, bih1, bhh1, pre, 512);
  k_lstm7<true><<<64, 512, 0, stream>>>(pre, Whh1, hlast);

  // FC: out[64,768] = hlast @ fcW^T + fcb
  dim3 gF(1, NOUT / 64);
  k_gemm_abt<128, false><<<gF, 256, 0, stream>>>(hlast, fcW, fcb, nullptr, out, NOUT);
}